// Round 12
// baseline (4588.903 us; speedup 1.0000x reference)
//
#include <hip/hip_runtime.h>
#include <hip/hip_bf16.h>

// RNNModel: bidirectional 2-layer LSTM + position attention + decode.
// T=256 B=32 H=1024 E=1024 V=32000 L=2. Device float buffers are fp32.
//
// R11 -> R12: lstm floor (5 falsified sync theories) left alone; attack the
// ~1.1ms GEMM remainder past the m97 ~900TF ceiling with a 256^2 phased
// schedule (gemm8): 8 waves, BK=64, 128KB dbuf LDS, width-16 global_load_lds
// with both-sides XOR swizzle, counted vmcnt(8) (never 0 in-loop), raw
// s_barrier phase pairs, setprio around MFMA clusters, bijective XCD swizzle.
// Used for gi/trans/decode (fast path). lstm_layer = R6/R11 verbatim.

using bf16 = __hip_bfloat16;
typedef __attribute__((ext_vector_type(8))) __bf16 bf16x8;
typedef __attribute__((ext_vector_type(4))) float f32x4;
typedef __attribute__((ext_vector_type(4))) short short4v;

#define T_ 256
#define B_ 32
#define H_ 1024
#define V_ 32000

__device__ __forceinline__ float b2f(bf16 x) { return __bfloat162float(x); }
__device__ __forceinline__ bf16 f2b(float x) { return __float2bfloat16(x); }
__device__ __forceinline__ float us2f(unsigned short u) {
  union { unsigned u; float f; } w; w.u = ((unsigned)u) << 16; return w.f;
}
__device__ __forceinline__ void st4(bf16* dst, float4 f) {
  union { bf16 h[4]; short4v s; } u;
  u.h[0] = f2b(f.x); u.h[1] = f2b(f.y); u.h[2] = f2b(f.z); u.h[3] = f2b(f.w);
  *reinterpret_cast<short4v*>(dst) = u.s;
}
__device__ __forceinline__ bf16x8 cvt8(float4 a, float4 b) {
  union { bf16 h[8]; bf16x8 v; } u;
  u.h[0] = f2b(a.x); u.h[1] = f2b(a.y); u.h[2] = f2b(a.z); u.h[3] = f2b(a.w);
  u.h[4] = f2b(b.x); u.h[5] = f2b(b.y); u.h[6] = f2b(b.z); u.h[7] = f2b(b.w);
  return u.v;
}
// async global->LDS, 16B per lane; LDS dest = wave-uniform base + lane*16
__device__ __forceinline__ void gload_lds16(const bf16* g, bf16* l) {
  __builtin_amdgcn_global_load_lds(
      (const __attribute__((address_space(1))) void*)g,
      (__attribute__((address_space(3))) void*)l, 16, 0, 0);
}

// ---------------------------------------------------------------------------
// fp32 -> bf16 bulk convert (n % 2048 == 0)
// ---------------------------------------------------------------------------
__global__ __launch_bounds__(256)
void cvt_f32_bf16(const float* __restrict__ src, bf16* __restrict__ dst, long n)
{
  long i = ((long)blockIdx.x * 256 + threadIdx.x) * 8;
  if (i >= n) return;
  float4 a = *reinterpret_cast<const float4*>(src + i);
  float4 b = *reinterpret_cast<const float4*>(src + i + 4);
  st4(dst + i, a); st4(dst + i + 4, b);
}

// ---------------------------------------------------------------------------
// Embedding gather + fp32->bf16
// ---------------------------------------------------------------------------
__global__ __launch_bounds__(128)
void embed_gather(const int* __restrict__ dl, const int* __restrict__ dr,
                  const float* __restrict__ emb,
                  bf16* __restrict__ xL, bf16* __restrict__ xR)
{
  int wg = blockIdx.x;          // 0..16383
  int d  = wg >> 13;
  int r  = wg & 8191;           // t*32+b
  int t  = r >> 5, b = r & 31;
  int tok = d ? dr[(T_ - 1 - t) * B_ + b] : dl[r];
  const float* src = emb + (long)tok * H_;
  bf16* dst = (d ? xR : xL) + (long)r * H_;
  int e = threadIdx.x * 8;
  float4 a = *reinterpret_cast<const float4*>(src + e);
  float4 c = *reinterpret_cast<const float4*>(src + e + 4);
  st4(dst + e, a); st4(dst + e + 4, c);
}

// ---------------------------------------------------------------------------
// FALLBACK: C = A(bf16) @ B(NxK fp32)^T, reg-staged (proven R3-R11 path)
// ---------------------------------------------------------------------------
#define LSTRIDE 40

template<int ACT, int HASBIAS, int OUTF32>
__global__ __launch_bounds__(256)
void gemm_bt(const bf16* __restrict__ A, const float* __restrict__ Bwf,
             const float* __restrict__ bias, void* __restrict__ Cv,
             int M, int N, int K)
{
  __shared__ __align__(16) bf16 As[128 * LSTRIDE];
  __shared__ __align__(16) bf16 Bs[128 * LSTRIDE];
  const int tid  = threadIdx.x;
  const int lane = tid & 63;
  const int wave = tid >> 6;
  const int wm = wave >> 1, wn = wave & 1;
  const long bm = blockIdx.x, bn = blockIdx.y;

  const bf16*  Ag = A + bm * 128 * (long)K;
  const float* Bg = Bwf + bn * 128 * (long)K;

  f32x4 acc[4][4] = {};

  const int nk = K >> 5;
  for (int kt = 0; kt < nk; ++kt) {
    const int k0 = kt * 32;
    __syncthreads();
    #pragma unroll
    for (int j = 0; j < 2; ++j) {
      int chunk = j * 256 + tid;
      int row = chunk >> 2, c4 = chunk & 3;
      *reinterpret_cast<bf16x8*>(&As[row * LSTRIDE + c4 * 8]) =
          *reinterpret_cast<const bf16x8*>(&Ag[(long)row * K + k0 + c4 * 8]);
    }
    #pragma unroll
    for (int j = 0; j < 4; ++j) {
      int chunk = j * 256 + tid;
      int row = chunk >> 3, c4f = chunk & 7;
      float4 f = *reinterpret_cast<const float4*>(&Bg[(long)row * K + k0 + c4f * 4]);
      st4(&Bs[row * LSTRIDE + c4f * 4], f);
    }
    __syncthreads();
    bf16x8 af[4], bfr[4];
    #pragma unroll
    for (int m = 0; m < 4; ++m)
      af[m] = *reinterpret_cast<const bf16x8*>(
          &As[(wm * 64 + m * 16 + (lane & 15)) * LSTRIDE + (lane >> 4) * 8]);
    #pragma unroll
    for (int n = 0; n < 4; ++n)
      bfr[n] = *reinterpret_cast<const bf16x8*>(
          &Bs[(wn * 64 + n * 16 + (lane & 15)) * LSTRIDE + (lane >> 4) * 8]);
    #pragma unroll
    for (int m = 0; m < 4; ++m)
      #pragma unroll
      for (int n = 0; n < 4; ++n)
        acc[m][n] = __builtin_amdgcn_mfma_f32_16x16x32_bf16(af[m], bfr[n], acc[m][n], 0, 0, 0);
  }

  #pragma unroll
  for (int m = 0; m < 4; ++m) {
    int row = (int)bm * 128 + wm * 64 + m * 16 + ((lane >> 4) << 2);
    #pragma unroll
    for (int n = 0; n < 4; ++n) {
      int col = (int)bn * 128 + wn * 64 + n * 16 + (lane & 15);
      float bv = HASBIAS ? bias[col] : 0.f;
      #pragma unroll
      for (int j = 0; j < 4; ++j) {
        float v = acc[m][n][j] + bv;
        if (ACT) v = tanhf(v);
        long off = (long)(row + j) * N + col;
        if (OUTF32) reinterpret_cast<float*>(Cv)[off] = v;
        else        reinterpret_cast<bf16*>(Cv)[off] = f2b(v);
      }
    }
  }
}

// ---------------------------------------------------------------------------
// FAST: 256x256 phased GEMM, C = A(bf16) @ B(NxK bf16)^T [+bias][tanh].
// 8 waves (2x4), BK=64, LDS = 2 dbuf x (A[256][64]+B[256][64]) = 128KB.
// Staging: width-16 global_load_lds, 8 wave-instr groups per K-tile, source
// pre-swizzled with k-chunk = (c&7)^(r&7); reads use slot u^(r&7) (T2).
// Pipeline: issue all 8 next-tile loads at phase 0, then vmcnt(8) -- waits
// exactly the current tile, keeps 8 in flight (T4, never 0 in-loop). Raw
// s_barrier phase pairs + setprio around 16-MFMA clusters (T3/T5).
// M%256==0, N%256==0, K%64==0, gridDim.x%8==0 (bijective XCD swizzle, T1).
// ---------------------------------------------------------------------------
template<int ACT, int HASBIAS, int OUTF32>
__global__ __launch_bounds__(512, 1)
void gemm8(const bf16* __restrict__ A, const bf16* __restrict__ Bw,
           const float* __restrict__ bias, void* __restrict__ Cv,
           int M, int N, int K, int mt)
{
  __shared__ __align__(16) bf16 As[2][256 * 64];
  __shared__ __align__(16) bf16 Bs[2][256 * 64];
  const int tid  = threadIdx.x;
  const int lane = tid & 63;
  const int wave = tid >> 6;
  const int wm = wave >> 2, wn = wave & 3;

  // bijective XCD swizzle: consecutive swz within an XCD share bn
  const int nwg = (int)gridDim.x;
  const int cpx = nwg >> 3;
  const int bid = (int)blockIdx.x;
  const int swz = (bid & 7) * cpx + (bid >> 3);
  const long bm = swz % mt, bn = swz / mt;

  const bf16* Ag = A  + bm * 256 * (long)K;
  const bf16* Bg = Bw + bn * 256 * (long)K;

  f32x4 acc[8][4] = {};
  const int nt = K >> 6;

  // --- stage one K-tile (8 wave-instr groups; chunks c = gl*512+tid) ---
  auto stage = [&](int buf, int kt) {
    const int k0 = kt * 64;
    #pragma unroll
    for (int g = 0; g < 8; ++g) {
      const int gl = g & 3;
      const int c  = gl * 512 + tid;
      const int r  = c >> 3;
      const int sl = (c & 7) ^ (r & 7);        // pre-swizzled source k-chunk
      if (g < 4)
        gload_lds16(Ag + (long)r * K + k0 + sl * 8, &As[buf][gl * 4096 + wave * 512]);
      else
        gload_lds16(Bg + (long)r * K + k0 + sl * 8, &Bs[buf][gl * 4096 + wave * 512]);
    }
  };

  stage(0, 0);
  asm volatile("s_waitcnt vmcnt(0)" ::: "memory");
  __builtin_amdgcn_s_barrier();

  for (int j = 0; j < nt; ++j) {
    const int cur = j & 1, nxt = cur ^ 1;
    if (j + 1 < nt) {
      stage(nxt, j + 1);                        // 8 loads into other buffer
      asm volatile("s_waitcnt vmcnt(8)" ::: "memory");  // tile j resident
    } else {
      asm volatile("s_waitcnt vmcnt(0)" ::: "memory");
    }
    __builtin_amdgcn_s_barrier();               // cross-wave staging visible

    // B fragments for the whole K-tile (held across phases)
    bf16x8 bfr[4][2];
    #pragma unroll
    for (int fn = 0; fn < 4; ++fn)
      #pragma unroll
      for (int kk = 0; kk < 2; ++kk) {
        int rb = wn * 64 + fn * 16 + (lane & 15);
        int u  = (lane >> 4) + 4 * kk;
        bfr[fn][kk] = *reinterpret_cast<const bf16x8*>(
            &Bs[cur][rb * 64 + (u ^ (rb & 7)) * 8]);
      }

    #pragma unroll
    for (int p = 0; p < 4; ++p) {
      bf16x8 afr[2][2];
      #pragma unroll
      for (int q = 0; q < 2; ++q)
        #pragma unroll
        for (int kk = 0; kk < 2; ++kk) {
          int ra = wm * 128 + (p * 2 + q) * 16 + (lane & 15);
          int u  = (lane >> 4) + 4 * kk;
          afr[q][kk] = *reinterpret_cast<const bf16x8*>(
              &As[cur][ra * 64 + (u ^ (ra & 7)) * 8]);
        }
      __builtin_amdgcn_s_barrier();
      __builtin_amdgcn_s_setprio(1);
      #pragma unroll
      for (int q = 0; q < 2; ++q)
        #pragma unroll
        for (int fn = 0; fn < 4; ++fn) {
          acc[p * 2 + q][fn] = __builtin_amdgcn_mfma_f32_16x16x32_bf16(
              afr[q][0], bfr[fn][0], acc[p * 2 + q][fn], 0, 0, 0);
          acc[p * 2 + q][fn] = __builtin_amdgcn_mfma_f32_16x16x32_bf16(
              afr[q][1], bfr[fn][1], acc[p * 2 + q][fn], 0, 0, 0);
        }
      __builtin_amdgcn_s_setprio(0);
      __builtin_amdgcn_s_barrier();
    }
  }

  // D mapping: col=lane&15, row=(lane>>4)*4+jj  [m89/m91]
  #pragma unroll
  for (int fm = 0; fm < 8; ++fm) {
    int row = (int)bm * 256 + wm * 128 + fm * 16 + ((lane >> 4) << 2);
    #pragma unroll
    for (int fn = 0; fn < 4; ++fn) {
      int col = (int)bn * 256 + wn * 64 + fn * 16 + (lane & 15);
      float bv = HASBIAS ? bias[col] : 0.f;
      #pragma unroll
      for (int jj = 0; jj < 4; ++jj) {
        float v = acc[fm][fn][jj] + bv;
        if (ACT) v = tanhf(v);
        long off = (long)(row + jj) * N + col;
        if (OUTF32) reinterpret_cast<float*>(Cv)[off] = v;
        else        reinterpret_cast<bf16*>(Cv)[off] = f2b(v);
      }
    }
  }
}

// ---------------------------------------------------------------------------
// Persistent LSTM layer — R6 verbatim (fastest measured: ~1490us/layer).
// ---------------------------------------------------------------------------
__global__ __launch_bounds__(256, 1)
void lstm_layer(const bf16* __restrict__ WhhL, const bf16* __restrict__ WhhR,
                const bf16* __restrict__ giL,  const bf16* __restrict__ giR,
                const float* __restrict__ bihL, const float* __restrict__ bhhL,
                const float* __restrict__ bihR, const float* __restrict__ bhhR,
                const float* __restrict__ h0L, const float* __restrict__ h0R,
                const float* __restrict__ c0L, const float* __restrict__ c0R,
                bf16* __restrict__ houtL, bf16* __restrict__ houtR,
                int revR, unsigned* __restrict__ bar)
{
  const int d    = blockIdx.y;
  const int u0   = blockIdx.x * 16;
  const int tid  = threadIdx.x;
  const int lane = tid & 63;
  const int wq   = tid >> 6;
  const long BH  = (long)B_ * H_;

  const bf16*  Whh = d ? WhhR : WhhL;
  const bf16*  gi0 = d ? giR  : giL;
  const float* bi  = d ? bihR : bihL;
  const float* bh  = d ? bhhR : bhhL;
  const float* h0  = d ? h0R  : h0L;
  const float* c0  = d ? c0R  : c0L;
  bf16* hout       = d ? houtR : houtL;
  const int rev    = d ? revR : 0;
  unsigned* cnt    = bar + d;

  (void)__hip_atomic_load(cnt, __ATOMIC_ACQUIRE, __HIP_MEMORY_SCOPE_AGENT);

  const int klo = (lane >> 4) * 8;

  bf16x8 w_reg[4][8];
  #pragma unroll
  for (int g = 0; g < 4; ++g) {
    const bf16* p = Whh + ((long)g * H_ + u0 + (lane & 15)) * H_ + wq * 256 + klo;
    #pragma unroll
    for (int q = 0; q < 8; ++q)
      w_reg[g][q] = *reinterpret_cast<const bf16x8*>(p + q * 32);
  }

  const int b  = tid >> 3;
  const int u  = (tid & 7) * 2;
  const int ug = u0 + u;

  float bsum[4][2];
  #pragma unroll
  for (int g = 0; g < 4; ++g) {
    bsum[g][0] = bi[g * H_ + ug]     + bh[g * H_ + ug];
    bsum[g][1] = bi[g * H_ + ug + 1] + bh[g * H_ + ug + 1];
  }
  float cc0 = c0[(long)b * H_ + ug];
  float cc1 = c0[(long)b * H_ + ug + 1];

  __shared__ float gbuf[4][4][32][16];

  for (int s = 0; s < T_; ++s) {
    unsigned giv[4];
    {
      const bf16* gis = gi0 + (long)s * (B_ * 4 * H_) + (long)b * (4 * H_);
      #pragma unroll
      for (int g = 0; g < 4; ++g)
        giv[g] = *reinterpret_cast<const unsigned*>(&gis[g * H_ + ug]);
    }

    f32x4 acc[4][2];
    #pragma unroll
    for (int g = 0; g < 4; ++g) {
      acc[g][0] = f32x4{0.f, 0.f, 0.f, 0.f};
      acc[g][1] = f32x4{0.f, 0.f, 0.f, 0.f};
    }

    if (s == 0) {
      const float* ap0 = h0 + (long)(lane & 15) * H_ + wq * 256 + klo;
      const float* ap1 = ap0 + 16L * H_;
      #pragma unroll
      for (int q = 0; q < 8; ++q) {
        bf16x8 a0 = cvt8(*reinterpret_cast<const float4*>(ap0 + q * 32),
                         *reinterpret_cast<const float4*>(ap0 + q * 32 + 4));
        bf16x8 a1 = cvt8(*reinterpret_cast<const float4*>(ap1 + q * 32),
                         *reinterpret_cast<const float4*>(ap1 + q * 32 + 4));
        #pragma unroll
        for (int g = 0; g < 4; ++g) {
          acc[g][0] = __builtin_amdgcn_mfma_f32_16x16x32_bf16(a0, w_reg[g][q], acc[g][0], 0, 0, 0);
          acc[g][1] = __builtin_amdgcn_mfma_f32_16x16x32_bf16(a1, w_reg[g][q], acc[g][1], 0, 0, 0);
        }
      }
    } else {
      const bf16* hp  = hout + (long)(rev ? (T_ - s) : (s - 1)) * BH;
      const bf16* ap0 = hp + (long)(lane & 15) * H_ + wq * 256 + klo;
      const bf16* ap1 = ap0 + 16L * H_;
      #pragma unroll
      for (int q = 0; q < 8; ++q) {
        bf16x8 a0 = *reinterpret_cast<const bf16x8*>(ap0 + q * 32);
        bf16x8 a1 = *reinterpret_cast<const bf16x8*>(ap1 + q * 32);
        #pragma unroll
        for (int g = 0; g < 4; ++g) {
          acc[g][0] = __builtin_amdgcn_mfma_f32_16x16x32_bf16(a0, w_reg[g][q], acc[g][0], 0, 0, 0);
          acc[g][1] = __builtin_amdgcn_mfma_f32_16x16x32_bf16(a1, w_reg[g][q], acc[g][1], 0, 0, 0);
        }
      }
    }

    {
      int cr = (lane >> 4) << 2, ccu = lane & 15;
      #pragma unroll
      for (int g = 0; g < 4; ++g)
        #pragma unroll
        for (int j = 0; j < 4; ++j) {
          gbuf[wq][g][cr + j][ccu]      = acc[g][0][j];
          gbuf[wq][g][16 + cr + j][ccu] = acc[g][1][j];
        }
    }
    __syncthreads();

    {
      float g4[4][2];
      #pragma unroll
      for (int g = 0; g < 4; ++g) {
        float p0 = gbuf[0][g][b][u]     + gbuf[1][g][b][u];
        float p1 = gbuf[2][g][b][u]     + gbuf[3][g][b][u];
        float q0 = gbuf[0][g][b][u + 1] + gbuf[1][g][b][u + 1];
        float q1 = gbuf[2][g][b][u + 1] + gbuf[3][g][b][u + 1];
        g4[g][0] = (p0 + p1) + us2f((unsigned short)(giv[g] & 0xffffu)) + bsum[g][0];
        g4[g][1] = (q0 + q1) + us2f((unsigned short)(giv[g] >> 16))     + bsum[g][1];
      }
      float si0 = 1.f / (1.f + expf(-g4[0][0])), si1 = 1.f / (1.f + expf(-g4[0][1]));
      float sf0 = 1.f / (1.f + expf(-g4[1][0])), sf1 = 1.f / (1.f + expf(-g4[1][1]));
      float tg0 = tanhf(g4[2][0]),               tg1 = tanhf(g4[2][1]);
      float so0 = 1.f / (1.f + expf(-g4[3][0])), so1 = 1.f / (1.f + expf(-g4[3][1]));
      cc0 = sf0 * cc0 + si0 * tg0;
      cc1 = sf1 * cc1 + si1 * tg1;
      float hn0 = so0 * tanhf(cc0);
      float hn1 = so1 * tanhf(cc1);
      union { bf16 h[2]; unsigned w; } up;
      up.h[0] = f2b(hn0); up.h[1] = f2b(hn1);
      long wIdx = rev ? (long)(T_ - 1 - s) : (long)s;
      __hip_atomic_store(
          reinterpret_cast<unsigned*>(&hout[wIdx * BH + (long)b * H_ + ug]),
          up.w, __ATOMIC_RELAXED, __HIP_MEMORY_SCOPE_AGENT);
    }

    if (s + 1 < T_) {
      __syncthreads();
      if (tid == 0) {
        __hip_atomic_fetch_add(cnt, 1u, __ATOMIC_RELAXED, __HIP_MEMORY_SCOPE_AGENT);
        unsigned tgt = 64u * (unsigned)(s + 1);
        while (__hip_atomic_load(cnt, __ATOMIC_RELAXED, __HIP_MEMORY_SCOPE_AGENT) < tgt)
          __builtin_amdgcn_s_sleep(2);
      }
      __syncthreads();
    }
  }
}

// ---------------------------------------------------------------------------
// a = outL@w1 + outR@w2 + ab; sL = outL@w3; sR = outR@w3   (one WG per (t,b))
// ---------------------------------------------------------------------------
__global__ __launch_bounds__(256)
void attn_scores(const bf16* __restrict__ outL, const bf16* __restrict__ outR,
                 const float* __restrict__ attn_w, const float* __restrict__ attn_b,
                 float* __restrict__ a, float* __restrict__ sL, float* __restrict__ sR)
{
  int r = blockIdx.x;
  int tid = threadIdx.x;
  const bf16* oL = outL + (long)r * H_;
  const bf16* oR = outR + (long)r * H_;
  int e = tid * 4;
  float pa = 0.f, pl = 0.f, pr = 0.f;
  #pragma unroll
  for (int j = 0; j < 4; ++j) {
    float l_ = b2f(oL[e + j]), r_ = b2f(oR[e + j]);
    float w1 = attn_w[e + j];
    float w2 = attn_w[H_ + e + j];
    float w3 = attn_w[2 * H_ + e + j];
    pa += w1 * l_ + w2 * r_;
    pl += w3 * l_;
    pr += w3 * r_;
  }
  #pragma unroll
  for (int off = 32; off > 0; off >>= 1) {
    pa += __shfl_down(pa, off);
    pl += __shfl_down(pl, off);
    pr += __shfl_down(pr, off);
  }
  __shared__ float red[3][4];
  int wave = tid >> 6, lane = tid & 63;
  if (lane == 0) { red[0][wave] = pa; red[1][wave] = pl; red[2][wave] = pr; }
  __syncthreads();
  if (tid == 0) {
    a[r]  = red[0][0] + red[0][1] + red[0][2] + red[0][3] + attn_b[0];
    sL[r] = red[1][0] + red[1][1] + red[1][2] + red[1][3];
    sR[r] = red[2][0] + red[2][1] + red[2][2] + red[2][3];
  }
}

// ---------------------------------------------------------------------------
// softmax over k=0..256 of tanh(a[i,b] + (k<=i ? sL[k,b] : sR[k-1,b]))
// ---------------------------------------------------------------------------
__global__ __launch_bounds__(64)
void attn_softmax(const float* __restrict__ a, const float* __restrict__ sL,
                  const float* __restrict__ sR, float* __restrict__ p)
{
  int i = blockIdx.x, b = blockIdx.y;
  int lane = threadIdx.x;
  float av = a[i * B_ + b];
  float sc[5];
  float mx = -1e30f;
  #pragma unroll
  for (int q = 0; q < 5; ++q) {
    int k = lane + q * 64;
    float v = -1e30f;
    if (k < 257) {
      float ctx = (k <= i) ? sL[k * B_ + b] : sR[(k - 1) * B_ + b];
      v = tanhf(av + ctx);
    }
    sc[q] = v;
    mx = fmaxf(mx, v);
  }
  #pragma unroll
  for (int off = 32; off > 0; off >>= 1) mx = fmaxf(mx, __shfl_xor(mx, off));
  float sum = 0.f;
  #pragma unroll
  for (int q = 0; q < 5; ++q) {
    int k = lane + q * 64;
    float e = (k < 257) ? __expf(sc[q] - mx) : 0.f;
    sc[q] = e; sum += e;
  }
  #pragma unroll
  for (int off = 32; off > 0; off >>= 1) sum += __shfl_xor(sum, off);
  float inv = 1.f / sum;
  long base = ((long)b * T_ + i) * 257;
  #pragma unroll
  for (int q = 0; q < 5; ++q) {
    int k = lane + q * 64;
    if (k < 257) p[base + k] = sc[q] * inv;
  }
}

// ---------------------------------------------------------------------------
// h3[:, :, 0:H] = outL ; h3[:, :, H:2H] = outR
// ---------------------------------------------------------------------------
__global__ __launch_bounds__(256)
void h3_copy(const bf16* __restrict__ outL, const bf16* __restrict__ outR,
             bf16* __restrict__ h3)
{
  long gid = (long)blockIdx.x * 256 + threadIdx.x;
  long e = gid * 8;
  if (e >= (long)T_ * B_ * H_) return;
  long r = e >> 10; int h = (int)(e & 1023);
  *reinterpret_cast<bf16x8*>(&h3[r * 3 * H_ + h]) =
      *reinterpret_cast<const bf16x8*>(&outL[e]);
  *reinterpret_cast<bf16x8*>(&h3[r * 3 * H_ + H_ + h]) =
      *reinterpret_cast<const bf16x8*>(&outR[e]);
}

// ---------------------------------------------------------------------------
// cv[i,b,:] = sum_k p[i,k,b] * (k<=i ? outL[k,b,:] : outR[k-1,b,:]) -> h3[:,:,2H:3H]
// ---------------------------------------------------------------------------
__global__ __launch_bounds__(256)
void attn_cv(const float* __restrict__ p, const bf16* __restrict__ outL,
             const bf16* __restrict__ outR, bf16* __restrict__ h3)
{
  int b = blockIdx.y;
  int i0 = blockIdx.x * 16;
  int tid = threadIdx.x;
  __shared__ float ps[16][257];
  for (int idx = tid; idx < 16 * 257; idx += 256) {
    int ii = idx / 257, k = idx % 257;
    ps[ii][k] = p[((long)b * T_ + i0 + ii) * 257 + k];
  }
  __syncthreads();
  float acc[16][4] = {};
  int h0 = tid * 4;
  for (int k = 0; k < 257; ++k) {
    float vL[4] = {0.f, 0.f, 0.f, 0.f}, vR[4] = {0.f, 0.f, 0.f, 0.f};
    if (k < 256) {
      short4v v = *reinterpret_cast<const short4v*>(&outL[((long)k * B_ + b) * H_ + h0]);
      vL[0] = us2f((unsigned short)v[0]); vL[1] = us2f((unsigned short)v[1]);
      vL[2] = us2f((unsigned short)v[2]); vL[3] = us2f((unsigned short)v[3]);
    }
    if (k >= 1) {
      short4v v = *reinterpret_cast<const short4v*>(&outR[((long)(k - 1) * B_ + b) * H_ + h0]);
      vR[0] = us2f((unsigned short)v[0]); vR[1] = us2f((unsigned short)v[1]);
      vR[2] = us2f((unsigned short)v[2]); vR[3] = us2f((unsigned short)v[3]);
    }
    #pragma unroll
    for (int ii = 0; ii < 16; ++ii) {
      float pv = ps[ii][k];
      bool useL = (i0 + ii) >= k;
      #pragma unroll
      for (int j = 0; j < 4; ++j)
        acc[ii][j] += pv * (useL ? vL[j] : vR[j]);
    }
  }
  #pragma unroll
  for (int ii = 0; ii < 16; ++ii)
    #pragma unroll
    for (int j = 0; j < 4; ++j)
      h3[((long)(i0 + ii) * B_ + b) * 3 * H_ + 2 * H_ + h0 + j] = f2b(acc[ii][j]);
}

// ---------------------------------------------------------------------------
extern "C" void kernel_launch(void* const* d_in, const int* in_sizes, int n_in,
                              void* d_out, int out_size, void* d_ws, size_t ws_size,
                              hipStream_t stream)
{
  (void)in_sizes; (void)n_in; (void)out_size;
  const int*   data_left  = (const int*)  d_in[0];
  const int*   data_right = (const int*)  d_in[1];
  const float* h0_left    = (const float*)d_in[2];
  const float* c0_left    = (const float*)d_in[3];
  const float* h0_right   = (const float*)d_in[4];
  const float* c0_right   = (const float*)d_in[5];
  const float* emb        = (const float*)d_in[6];
  const float* Wih_l      = (const float*)d_in[7];
  const float* Whh_l      = (const float*)d_in[8];
  const float* bih_l      = (const float*)d_in[9];
  const float* bhh_l      = (const float*)d_in[10];
  const float* Wih_r      = (const float*)d_in[11];
  const float* Whh_r      = (const float*)d_in[12];
  const float* bih_r      = (const float*)d_in[13];
  const float* bhh_r      = (const float*)d_in[14];
  const float* attn_w     = (const float*)d_in[15];
  const float* attn_b     = (const float*)d_in[16];
  const float* trans_w    = (const float*)d_in[17];
  const float* trans_b    = (const float*)d_in[18];
  const float* dec_w      = (const float*)d_in[19];
  const float* dec_b      = (const float*)d_in[20];

  // ---- workspace layout ----
  char* ws = (char*)d_ws;
  bf16*     XL   = (bf16*)    (ws + 0L);
  bf16*     XR   = (bf16*)    (ws + 16777216L);
  bf16*     GI_L = (bf16*)    (ws + 33554432L);
  bf16*     GI_R = (bf16*)    (ws + 100663296L);
  bf16*     H0L  = (bf16*)    (ws + 167772160L);
  bf16*     H0R  = (bf16*)    (ws + 184549376L);
  unsigned* BAR  = (unsigned*)(ws + 201326592L);
  bf16*     WHHB = (bf16*)    (ws + 201588736L);   // 33.6MB, ends 235143168
  bf16*     WIHB   = (bf16*)  (ws + 235143168L);   // 33.6MB, ends 268697600
  bf16*     TRANSB = (bf16*)  (ws + 268697600L);   // 6.3MB,  ends 274989056
  bf16*     DECB   = (bf16*)  (ws + 274989056L);   // 65.5MB, ends 340525056
  const bool fast = ws_size >= 340525056UL;
  // overlays
  bf16*  O1L  = XL;
  bf16*  O1R  = XR;
  bf16*  H3   = GI_L;
  float* P_   = (float*)(ws + 100663296L);
  float* A_   = (float*)(ws + 109084672L);
  float* SL_  = (float*)(ws + 109117440L);
  float* SR_  = (float*)(ws + 109150208L);
  bf16*  PRED = (bf16*) (ws + 109182976L);

  const long BH  = (long)B_ * H_;
  const long WL  = 4L * H_ * H_;
  bf16* WHHB_l = WHHB;
  bf16* WHHB_r = WHHB + 2 * WL;
  bf16* WIHB_l = WIHB;
  bf16* WIHB_r = WIHB + 2 * WL;

  // --- weight conversions ---
  cvt_f32_bf16<<<4096, 256, 0, stream>>>(Whh_l, WHHB_l, 2 * WL);
  cvt_f32_bf16<<<4096, 256, 0, stream>>>(Whh_r, WHHB_r, 2 * WL);
  if (fast) {
    cvt_f32_bf16<<<4096, 256, 0, stream>>>(Wih_l, WIHB_l, 2 * WL);
    cvt_f32_bf16<<<4096, 256, 0, stream>>>(Wih_r, WIHB_r, 2 * WL);
    cvt_f32_bf16<<<1536, 256, 0, stream>>>(trans_w, TRANSB, (long)H_ * 3 * H_);
    cvt_f32_bf16<<<16000, 256, 0, stream>>>(dec_w, DECB, (long)V_ * H_);
  }

  // --- embeddings ---
  embed_gather<<<16384, 128, 0, stream>>>(data_left, data_right, emb, XL, XR);

  // --- layer 0 input GEMMs ---
  if (fast) {
    gemm8<0,0,0><<<512, 512, 0, stream>>>(XL, WIHB_l, nullptr, GI_L, 8192, 4096, 1024, 32);
    gemm8<0,0,0><<<512, 512, 0, stream>>>(XR, WIHB_r, nullptr, GI_R, 8192, 4096, 1024, 32);
  } else {
    gemm_bt<0,0,0><<<dim3(64, 32), 256, 0, stream>>>(XL, Wih_l, nullptr, GI_L, 8192, 4096, 1024);
    gemm_bt<0,0,0><<<dim3(64, 32), 256, 0, stream>>>(XR, Wih_r, nullptr, GI_R, 8192, 4096, 1024);
  }

  // --- layer 0 recurrence (R6) ---
  hipMemsetAsync(BAR, 0, 256, stream);
  lstm_layer<<<dim3(64, 2), 256, 0, stream>>>(
      WHHB_l, WHHB_r, GI_L, GI_R,
      bih_l, bhh_l, bih_r, bhh_r,
      h0_left, h0_right, c0_left, c0_right,
      H0L, H0R, 0, BAR);

  // --- layer 1 input GEMMs ---
  if (fast) {
    gemm8<0,0,0><<<512, 512, 0, stream>>>(H0L, WIHB_l + WL, nullptr, GI_L, 8192, 4096, 1024, 32);
    gemm8<0,0,0><<<512, 512, 0, stream>>>(H0R, WIHB_r + WL, nullptr, GI_R, 8192, 4096, 1024, 32);
  } else {
    gemm_bt<0,0,0><<<dim3(64, 32), 256, 0, stream>>>(H0L, Wih_l + WL, nullptr, GI_L, 8192, 4096, 1024);
    gemm_bt<0,0,0><<<dim3(64, 32), 256, 0, stream>>>(H0R, Wih_r + WL, nullptr, GI_R, 8192, 4096, 1024);
  }

  // --- layer 1 recurrence (right dir in original time order) ---
  hipMemsetAsync(BAR, 0, 256, stream);
  lstm_layer<<<dim3(64, 2), 256, 0, stream>>>(
      WHHB_l + WL, WHHB_r + WL, GI_L, GI_R,
      bih_l + 4 * H_, bhh_l + 4 * H_, bih_r + 4 * H_, bhh_r + 4 * H_,
      h0_left + BH, h0_right + BH, c0_left + BH, c0_right + BH,
      O1L, O1R, 1, BAR);

  // --- attention ---
  attn_scores<<<8192, 256, 0, stream>>>(O1L, O1R, attn_w, attn_b, A_, SL_, SR_);
  attn_softmax<<<dim3(256, 32), 64, 0, stream>>>(A_, SL_, SR_, P_);
  h3_copy<<<4096, 256, 0, stream>>>(O1L, O1R, H3);
  attn_cv<<<dim3(16, 32), 256, 0, stream>>>(P_, O1L, O1R, H3);

  // --- trans (tanh) + decode ---
  if (fast) {
    gemm8<1,1,0><<<128, 512, 0, stream>>>(H3, TRANSB, trans_b, PRED, 8192, 1024, 3072, 32);
    gemm8<0,1,1><<<4000, 512, 0, stream>>>(PRED, DECB, dec_b, d_out, 8192, 32000, 1024, 32);
  } else {
    gemm_bt<1,1,0><<<dim3(64, 8),   256, 0, stream>>>(H3,   trans_w, trans_b, PRED, 8192, 1024, 3072);
    gemm_bt<0,1,1><<<dim3(64, 250), 256, 0, stream>>>(PRED, dec_w,   dec_b,   d_out, 8192, 32000, 1024);
  }
}

// Round 13
// 4410.590 us; speedup vs baseline: 1.0404x; 1.0404x over previous
//
#include <hip/hip_runtime.h>
#include <hip/hip_bf16.h>

// RNNModel: bidirectional 2-layer LSTM + position attention + decode.
// T=256 B=32 H=1024 E=1024 V=32000 L=2. Device float buffers are fp32.
//
// R12 -> R13: gemm8 (256^2 phased) measured == gemm_bb -> reverted to R11's
// gemm_bb everywhere (both structures wall-clock-equal at these shapes ->
// GEMMs operand-stream/launch bound, not schedule bound). One lstm tweak:
// prefetch gi(s+1) during the barrier wait (after h-drain syncthreads +
// signal, before poll completes) -- removes gi-load jitter from the
// max-of-64-WGs barrier statistic. R6 protocol otherwise untouched.

using bf16 = __hip_bfloat16;
typedef __attribute__((ext_vector_type(8))) __bf16 bf16x8;
typedef __attribute__((ext_vector_type(4))) float f32x4;
typedef __attribute__((ext_vector_type(4))) short short4v;

#define T_ 256
#define B_ 32
#define H_ 1024
#define V_ 32000

__device__ __forceinline__ float b2f(bf16 x) { return __bfloat162float(x); }
__device__ __forceinline__ bf16 f2b(float x) { return __float2bfloat16(x); }
__device__ __forceinline__ float us2f(unsigned short u) {
  union { unsigned u; float f; } w; w.u = ((unsigned)u) << 16; return w.f;
}
__device__ __forceinline__ void st4(bf16* dst, float4 f) {
  union { bf16 h[4]; short4v s; } u;
  u.h[0] = f2b(f.x); u.h[1] = f2b(f.y); u.h[2] = f2b(f.z); u.h[3] = f2b(f.w);
  *reinterpret_cast<short4v*>(dst) = u.s;
}
__device__ __forceinline__ bf16x8 cvt8(float4 a, float4 b) {
  union { bf16 h[8]; bf16x8 v; } u;
  u.h[0] = f2b(a.x); u.h[1] = f2b(a.y); u.h[2] = f2b(a.z); u.h[3] = f2b(a.w);
  u.h[4] = f2b(b.x); u.h[5] = f2b(b.y); u.h[6] = f2b(b.z); u.h[7] = f2b(b.w);
  return u.v;
}
// async global->LDS, 16B per lane; LDS dest = wave-uniform base + lane*16
__device__ __forceinline__ void gload_lds16(const bf16* g, bf16* l) {
  __builtin_amdgcn_global_load_lds(
      (const __attribute__((address_space(1))) void*)g,
      (__attribute__((address_space(3))) void*)l, 16, 0, 0);
}

// ---------------------------------------------------------------------------
// fp32 -> bf16 bulk convert (n % 2048 == 0)
// ---------------------------------------------------------------------------
__global__ __launch_bounds__(256)
void cvt_f32_bf16(const float* __restrict__ src, bf16* __restrict__ dst, long n)
{
  long i = ((long)blockIdx.x * 256 + threadIdx.x) * 8;
  if (i >= n) return;
  float4 a = *reinterpret_cast<const float4*>(src + i);
  float4 b = *reinterpret_cast<const float4*>(src + i + 4);
  st4(dst + i, a); st4(dst + i + 4, b);
}

// ---------------------------------------------------------------------------
// Embedding gather + fp32->bf16
// ---------------------------------------------------------------------------
__global__ __launch_bounds__(128)
void embed_gather(const int* __restrict__ dl, const int* __restrict__ dr,
                  const float* __restrict__ emb,
                  bf16* __restrict__ xL, bf16* __restrict__ xR)
{
  int wg = blockIdx.x;          // 0..16383
  int d  = wg >> 13;
  int r  = wg & 8191;           // t*32+b
  int t  = r >> 5, b = r & 31;
  int tok = d ? dr[(T_ - 1 - t) * B_ + b] : dl[r];
  const float* src = emb + (long)tok * H_;
  bf16* dst = (d ? xR : xL) + (long)r * H_;
  int e = threadIdx.x * 8;
  float4 a = *reinterpret_cast<const float4*>(src + e);
  float4 c = *reinterpret_cast<const float4*>(src + e + 4);
  st4(dst + e, a); st4(dst + e + 4, c);
}

// ---------------------------------------------------------------------------
// FALLBACK: C = A(bf16) @ B(NxK fp32)^T, reg-staged (proven R3-R11 path)
// ---------------------------------------------------------------------------
#define LSTRIDE 40

template<int ACT, int HASBIAS, int OUTF32>
__global__ __launch_bounds__(256)
void gemm_bt(const bf16* __restrict__ A, const float* __restrict__ Bwf,
             const float* __restrict__ bias, void* __restrict__ Cv,
             int M, int N, int K)
{
  __shared__ __align__(16) bf16 As[128 * LSTRIDE];
  __shared__ __align__(16) bf16 Bs[128 * LSTRIDE];
  const int tid  = threadIdx.x;
  const int lane = tid & 63;
  const int wave = tid >> 6;
  const int wm = wave >> 1, wn = wave & 1;
  const long bm = blockIdx.x, bn = blockIdx.y;

  const bf16*  Ag = A + bm * 128 * (long)K;
  const float* Bg = Bwf + bn * 128 * (long)K;

  f32x4 acc[4][4] = {};

  const int nk = K >> 5;
  for (int kt = 0; kt < nk; ++kt) {
    const int k0 = kt * 32;
    __syncthreads();
    #pragma unroll
    for (int j = 0; j < 2; ++j) {
      int chunk = j * 256 + tid;
      int row = chunk >> 2, c4 = chunk & 3;
      *reinterpret_cast<bf16x8*>(&As[row * LSTRIDE + c4 * 8]) =
          *reinterpret_cast<const bf16x8*>(&Ag[(long)row * K + k0 + c4 * 8]);
    }
    #pragma unroll
    for (int j = 0; j < 4; ++j) {
      int chunk = j * 256 + tid;
      int row = chunk >> 3, c4f = chunk & 7;
      float4 f = *reinterpret_cast<const float4*>(&Bg[(long)row * K + k0 + c4f * 4]);
      st4(&Bs[row * LSTRIDE + c4f * 4], f);
    }
    __syncthreads();
    bf16x8 af[4], bfr[4];
    #pragma unroll
    for (int m = 0; m < 4; ++m)
      af[m] = *reinterpret_cast<const bf16x8*>(
          &As[(wm * 64 + m * 16 + (lane & 15)) * LSTRIDE + (lane >> 4) * 8]);
    #pragma unroll
    for (int n = 0; n < 4; ++n)
      bfr[n] = *reinterpret_cast<const bf16x8*>(
          &Bs[(wn * 64 + n * 16 + (lane & 15)) * LSTRIDE + (lane >> 4) * 8]);
    #pragma unroll
    for (int m = 0; m < 4; ++m)
      #pragma unroll
      for (int n = 0; n < 4; ++n)
        acc[m][n] = __builtin_amdgcn_mfma_f32_16x16x32_bf16(af[m], bfr[n], acc[m][n], 0, 0, 0);
  }

  #pragma unroll
  for (int m = 0; m < 4; ++m) {
    int row = (int)bm * 128 + wm * 64 + m * 16 + ((lane >> 4) << 2);
    #pragma unroll
    for (int n = 0; n < 4; ++n) {
      int col = (int)bn * 128 + wn * 64 + n * 16 + (lane & 15);
      float bv = HASBIAS ? bias[col] : 0.f;
      #pragma unroll
      for (int j = 0; j < 4; ++j) {
        float v = acc[m][n][j] + bv;
        if (ACT) v = tanhf(v);
        long off = (long)(row + j) * N + col;
        if (OUTF32) reinterpret_cast<float*>(Cv)[off] = v;
        else        reinterpret_cast<bf16*>(Cv)[off] = f2b(v);
      }
    }
  }
}

// ---------------------------------------------------------------------------
// FAST: C = A(bf16) @ B(NxK bf16)^T [+bias][tanh]; m97 structure (R11).
// 128x128 tile, BK=32, LINEAR LDS [128][32], global_load_lds width 16 for
// both operands, both-sides XOR swizzle.
// ---------------------------------------------------------------------------
template<int ACT, int HASBIAS, int OUTF32>
__global__ __launch_bounds__(256)
void gemm_bb(const bf16* __restrict__ A, const bf16* __restrict__ Bw,
             const float* __restrict__ bias, void* __restrict__ Cv,
             int M, int N, int K)
{
  __shared__ __align__(16) bf16 As[128 * 32];
  __shared__ __align__(16) bf16 Bs[128 * 32];
  const int tid  = threadIdx.x;
  const int lane = tid & 63;
  const int wave = tid >> 6;
  const int wm = wave >> 1, wn = wave & 1;
  const long bm = blockIdx.x, bn = blockIdx.y;

  const bf16* Ag = A  + bm * 128 * (long)K;
  const bf16* Bg = Bw + bn * 128 * (long)K;

  const int r0  = tid >> 2;                          // staging row (j adds 64)
  const int cgd = (tid & 3) ^ (r0 & 3);              // pre-swizzled source colg
  const int rsw = ((lane >> 4) ^ (lane & 3)) * 8;    // swizzled read slot (elems)

  f32x4 acc[4][4] = {};
  const int nk = K >> 5;
  for (int kt = 0; kt < nk; ++kt) {
    const int k0 = kt * 32;
    __syncthreads();                                 // LDS safe to overwrite
    #pragma unroll
    for (int j = 0; j < 2; ++j) {
      int row = j * 64 + r0;
      gload_lds16(Ag + (long)row * K + k0 + cgd * 8, As + (j * 256 + wave * 64) * 8);
      gload_lds16(Bg + (long)row * K + k0 + cgd * 8, Bs + (j * 256 + wave * 64) * 8);
    }
    __syncthreads();                                 // drains vmcnt before barrier
    bf16x8 af[4], bfr[4];
    #pragma unroll
    for (int m = 0; m < 4; ++m)
      af[m] = *reinterpret_cast<const bf16x8*>(
          &As[(wm * 64 + m * 16 + (lane & 15)) * 32 + rsw]);
    #pragma unroll
    for (int n = 0; n < 4; ++n)
      bfr[n] = *reinterpret_cast<const bf16x8*>(
          &Bs[(wn * 64 + n * 16 + (lane & 15)) * 32 + rsw]);
    #pragma unroll
    for (int m = 0; m < 4; ++m)
      #pragma unroll
      for (int n = 0; n < 4; ++n)
        acc[m][n] = __builtin_amdgcn_mfma_f32_16x16x32_bf16(af[m], bfr[n], acc[m][n], 0, 0, 0);
  }

  // D mapping: col=lane&15, row=(lane>>4)*4+j  [m89/m91]
  #pragma unroll
  for (int m = 0; m < 4; ++m) {
    int row = (int)bm * 128 + wm * 64 + m * 16 + ((lane >> 4) << 2);
    #pragma unroll
    for (int n = 0; n < 4; ++n) {
      int col = (int)bn * 128 + wn * 64 + n * 16 + (lane & 15);
      float bv = HASBIAS ? bias[col] : 0.f;
      #pragma unroll
      for (int j = 0; j < 4; ++j) {
        float v = acc[m][n][j] + bv;
        if (ACT) v = tanhf(v);
        long off = (long)(row + j) * N + col;
        if (OUTF32) reinterpret_cast<float*>(Cv)[off] = v;
        else        reinterpret_cast<bf16*>(Cv)[off] = f2b(v);
      }
    }
  }
}

// ---------------------------------------------------------------------------
// Persistent LSTM layer — R6 protocol + gi(s+1) prefetch during barrier wait.
// ---------------------------------------------------------------------------
__global__ __launch_bounds__(256, 1)
void lstm_layer(const bf16* __restrict__ WhhL, const bf16* __restrict__ WhhR,
                const bf16* __restrict__ giL,  const bf16* __restrict__ giR,
                const float* __restrict__ bihL, const float* __restrict__ bhhL,
                const float* __restrict__ bihR, const float* __restrict__ bhhR,
                const float* __restrict__ h0L, const float* __restrict__ h0R,
                const float* __restrict__ c0L, const float* __restrict__ c0R,
                bf16* __restrict__ houtL, bf16* __restrict__ houtR,
                int revR, unsigned* __restrict__ bar)
{
  const int d    = blockIdx.y;
  const int u0   = blockIdx.x * 16;
  const int tid  = threadIdx.x;
  const int lane = tid & 63;
  const int wq   = tid >> 6;
  const long BH  = (long)B_ * H_;
  const long B4H = (long)B_ * 4 * H_;

  const bf16*  Whh = d ? WhhR : WhhL;
  const bf16*  gi0 = d ? giR  : giL;
  const float* bi  = d ? bihR : bihL;
  const float* bh  = d ? bhhR : bhhL;
  const float* h0  = d ? h0R  : h0L;
  const float* c0  = d ? c0R  : c0L;
  bf16* hout       = d ? houtR : houtL;
  const int rev    = d ? revR : 0;
  unsigned* cnt    = bar + d;

  (void)__hip_atomic_load(cnt, __ATOMIC_ACQUIRE, __HIP_MEMORY_SCOPE_AGENT);

  const int klo = (lane >> 4) * 8;

  bf16x8 w_reg[4][8];
  #pragma unroll
  for (int g = 0; g < 4; ++g) {
    const bf16* p = Whh + ((long)g * H_ + u0 + (lane & 15)) * H_ + wq * 256 + klo;
    #pragma unroll
    for (int q = 0; q < 8; ++q)
      w_reg[g][q] = *reinterpret_cast<const bf16x8*>(p + q * 32);
  }

  const int b  = tid >> 3;
  const int u  = (tid & 7) * 2;
  const int ug = u0 + u;

  float bsum[4][2];
  #pragma unroll
  for (int g = 0; g < 4; ++g) {
    bsum[g][0] = bi[g * H_ + ug]     + bh[g * H_ + ug];
    bsum[g][1] = bi[g * H_ + ug + 1] + bh[g * H_ + ug + 1];
  }
  float cc0 = c0[(long)b * H_ + ug];
  float cc1 = c0[(long)b * H_ + ug + 1];

  __shared__ float gbuf[4][4][32][16];

  // gi(0) preload
  unsigned giv[4];
  {
    const bf16* gis = gi0 + (long)b * (4 * H_);
    #pragma unroll
    for (int g = 0; g < 4; ++g)
      giv[g] = *reinterpret_cast<const unsigned*>(&gis[g * H_ + ug]);
  }

  for (int s = 0; s < T_; ++s) {
    f32x4 acc[4][2];
    #pragma unroll
    for (int g = 0; g < 4; ++g) {
      acc[g][0] = f32x4{0.f, 0.f, 0.f, 0.f};
      acc[g][1] = f32x4{0.f, 0.f, 0.f, 0.f};
    }

    if (s == 0) {
      const float* ap0 = h0 + (long)(lane & 15) * H_ + wq * 256 + klo;
      const float* ap1 = ap0 + 16L * H_;
      #pragma unroll
      for (int q = 0; q < 8; ++q) {
        bf16x8 a0 = cvt8(*reinterpret_cast<const float4*>(ap0 + q * 32),
                         *reinterpret_cast<const float4*>(ap0 + q * 32 + 4));
        bf16x8 a1 = cvt8(*reinterpret_cast<const float4*>(ap1 + q * 32),
                         *reinterpret_cast<const float4*>(ap1 + q * 32 + 4));
        #pragma unroll
        for (int g = 0; g < 4; ++g) {
          acc[g][0] = __builtin_amdgcn_mfma_f32_16x16x32_bf16(a0, w_reg[g][q], acc[g][0], 0, 0, 0);
          acc[g][1] = __builtin_amdgcn_mfma_f32_16x16x32_bf16(a1, w_reg[g][q], acc[g][1], 0, 0, 0);
        }
      }
    } else {
      const bf16* hp  = hout + (long)(rev ? (T_ - s) : (s - 1)) * BH;
      const bf16* ap0 = hp + (long)(lane & 15) * H_ + wq * 256 + klo;
      const bf16* ap1 = ap0 + 16L * H_;
      #pragma unroll
      for (int q = 0; q < 8; ++q) {
        bf16x8 a0 = *reinterpret_cast<const bf16x8*>(ap0 + q * 32);
        bf16x8 a1 = *reinterpret_cast<const bf16x8*>(ap1 + q * 32);
        #pragma unroll
        for (int g = 0; g < 4; ++g) {
          acc[g][0] = __builtin_amdgcn_mfma_f32_16x16x32_bf16(a0, w_reg[g][q], acc[g][0], 0, 0, 0);
          acc[g][1] = __builtin_amdgcn_mfma_f32_16x16x32_bf16(a1, w_reg[g][q], acc[g][1], 0, 0, 0);
        }
      }
    }

    {
      int cr = (lane >> 4) << 2, ccu = lane & 15;
      #pragma unroll
      for (int g = 0; g < 4; ++g)
        #pragma unroll
        for (int j = 0; j < 4; ++j) {
          gbuf[wq][g][cr + j][ccu]      = acc[g][0][j];
          gbuf[wq][g][16 + cr + j][ccu] = acc[g][1][j];
        }
    }
    __syncthreads();

    {
      float g4[4][2];
      #pragma unroll
      for (int g = 0; g < 4; ++g) {
        float p0 = gbuf[0][g][b][u]     + gbuf[1][g][b][u];
        float p1 = gbuf[2][g][b][u]     + gbuf[3][g][b][u];
        float q0 = gbuf[0][g][b][u + 1] + gbuf[1][g][b][u + 1];
        float q1 = gbuf[2][g][b][u + 1] + gbuf[3][g][b][u + 1];
        g4[g][0] = (p0 + p1) + us2f((unsigned short)(giv[g] & 0xffffu)) + bsum[g][0];
        g4[g][1] = (q0 + q1) + us2f((unsigned short)(giv[g] >> 16))     + bsum[g][1];
      }
      float si0 = 1.f / (1.f + expf(-g4[0][0])), si1 = 1.f / (1.f + expf(-g4[0][1]));
      float sf0 = 1.f / (1.f + expf(-g4[1][0])), sf1 = 1.f / (1.f + expf(-g4[1][1]));
      float tg0 = tanhf(g4[2][0]),               tg1 = tanhf(g4[2][1]);
      float so0 = 1.f / (1.f + expf(-g4[3][0])), so1 = 1.f / (1.f + expf(-g4[3][1]));
      cc0 = sf0 * cc0 + si0 * tg0;
      cc1 = sf1 * cc1 + si1 * tg1;
      float hn0 = so0 * tanhf(cc0);
      float hn1 = so1 * tanhf(cc1);
      union { bf16 h[2]; unsigned w; } up;
      up.h[0] = f2b(hn0); up.h[1] = f2b(hn1);
      long wIdx = rev ? (long)(T_ - 1 - s) : (long)s;
      __hip_atomic_store(
          reinterpret_cast<unsigned*>(&hout[wIdx * BH + (long)b * H_ + ug]),
          up.w, __ATOMIC_RELAXED, __HIP_MEMORY_SCOPE_AGENT);
    }

    if (s + 1 < T_) {
      __syncthreads();  // implicit vmcnt(0): h stores completed
      if (tid == 0)     // signal arrival first
        __hip_atomic_fetch_add(cnt, 1u, __ATOMIC_RELAXED, __HIP_MEMORY_SCOPE_AGENT);
      // prefetch gi(s+1) while the barrier propagates / poll spins
      unsigned ngiv[4];
      {
        const bf16* gis = gi0 + (long)(s + 1) * B4H + (long)b * (4 * H_);
        #pragma unroll
        for (int g = 0; g < 4; ++g)
          ngiv[g] = *reinterpret_cast<const unsigned*>(&gis[g * H_ + ug]);
      }
      if (tid == 0) {
        unsigned tgt = 64u * (unsigned)(s + 1);
        while (__hip_atomic_load(cnt, __ATOMIC_RELAXED, __HIP_MEMORY_SCOPE_AGENT) < tgt)
          __builtin_amdgcn_s_sleep(2);
      }
      __syncthreads();
      #pragma unroll
      for (int g = 0; g < 4; ++g) giv[g] = ngiv[g];
    }
  }
}

// ---------------------------------------------------------------------------
// a = outL@w1 + outR@w2 + ab; sL = outL@w3; sR = outR@w3   (one WG per (t,b))
// ---------------------------------------------------------------------------
__global__ __launch_bounds__(256)
void attn_scores(const bf16* __restrict__ outL, const bf16* __restrict__ outR,
                 const float* __restrict__ attn_w, const float* __restrict__ attn_b,
                 float* __restrict__ a, float* __restrict__ sL, float* __restrict__ sR)
{
  int r = blockIdx.x;
  int tid = threadIdx.x;
  const bf16* oL = outL + (long)r * H_;
  const bf16* oR = outR + (long)r * H_;
  int e = tid * 4;
  float pa = 0.f, pl = 0.f, pr = 0.f;
  #pragma unroll
  for (int j = 0; j < 4; ++j) {
    float l_ = b2f(oL[e + j]), r_ = b2f(oR[e + j]);
    float w1 = attn_w[e + j];
    float w2 = attn_w[H_ + e + j];
    float w3 = attn_w[2 * H_ + e + j];
    pa += w1 * l_ + w2 * r_;
    pl += w3 * l_;
    pr += w3 * r_;
  }
  #pragma unroll
  for (int off = 32; off > 0; off >>= 1) {
    pa += __shfl_down(pa, off);
    pl += __shfl_down(pl, off);
    pr += __shfl_down(pr, off);
  }
  __shared__ float red[3][4];
  int wave = tid >> 6, lane = tid & 63;
  if (lane == 0) { red[0][wave] = pa; red[1][wave] = pl; red[2][wave] = pr; }
  __syncthreads();
  if (tid == 0) {
    a[r]  = red[0][0] + red[0][1] + red[0][2] + red[0][3] + attn_b[0];
    sL[r] = red[1][0] + red[1][1] + red[1][2] + red[1][3];
    sR[r] = red[2][0] + red[2][1] + red[2][2] + red[2][3];
  }
}

// ---------------------------------------------------------------------------
// softmax over k=0..256 of tanh(a[i,b] + (k<=i ? sL[k,b] : sR[k-1,b]))
// ---------------------------------------------------------------------------
__global__ __launch_bounds__(64)
void attn_softmax(const float* __restrict__ a, const float* __restrict__ sL,
                  const float* __restrict__ sR, float* __restrict__ p)
{
  int i = blockIdx.x, b = blockIdx.y;
  int lane = threadIdx.x;
  float av = a[i * B_ + b];
  float sc[5];
  float mx = -1e30f;
  #pragma unroll
  for (int q = 0; q < 5; ++q) {
    int k = lane + q * 64;
    float v = -1e30f;
    if (k < 257) {
      float ctx = (k <= i) ? sL[k * B_ + b] : sR[(k - 1) * B_ + b];
      v = tanhf(av + ctx);
    }
    sc[q] = v;
    mx = fmaxf(mx, v);
  }
  #pragma unroll
  for (int off = 32; off > 0; off >>= 1) mx = fmaxf(mx, __shfl_xor(mx, off));
  float sum = 0.f;
  #pragma unroll
  for (int q = 0; q < 5; ++q) {
    int k = lane + q * 64;
    float e = (k < 257) ? __expf(sc[q] - mx) : 0.f;
    sc[q] = e; sum += e;
  }
  #pragma unroll
  for (int off = 32; off > 0; off >>= 1) sum += __shfl_xor(sum, off);
  float inv = 1.f / sum;
  long base = ((long)b * T_ + i) * 257;
  #pragma unroll
  for (int q = 0; q < 5; ++q) {
    int k = lane + q * 64;
    if (k < 257) p[base + k] = sc[q] * inv;
  }
}

// ---------------------------------------------------------------------------
// h3[:, :, 0:H] = outL ; h3[:, :, H:2H] = outR
// ---------------------------------------------------------------------------
__global__ __launch_bounds__(256)
void h3_copy(const bf16* __restrict__ outL, const bf16* __restrict__ outR,
             bf16* __restrict__ h3)
{
  long gid = (long)blockIdx.x * 256 + threadIdx.x;
  long e = gid * 8;
  if (e >= (long)T_ * B_ * H_) return;
  long r = e >> 10; int h = (int)(e & 1023);
  *reinterpret_cast<bf16x8*>(&h3[r * 3 * H_ + h]) =
      *reinterpret_cast<const bf16x8*>(&outL[e]);
  *reinterpret_cast<bf16x8*>(&h3[r * 3 * H_ + H_ + h]) =
      *reinterpret_cast<const bf16x8*>(&outR[e]);
}

// ---------------------------------------------------------------------------
// cv[i,b,:] = sum_k p[i,k,b] * (k<=i ? outL[k,b,:] : outR[k-1,b,:]) -> h3[:,:,2H:3H]
// ---------------------------------------------------------------------------
__global__ __launch_bounds__(256)
void attn_cv(const float* __restrict__ p, const bf16* __restrict__ outL,
             const bf16* __restrict__ outR, bf16* __restrict__ h3)
{
  int b = blockIdx.y;
  int i0 = blockIdx.x * 16;
  int tid = threadIdx.x;
  __shared__ float ps[16][257];
  for (int idx = tid; idx < 16 * 257; idx += 256) {
    int ii = idx / 257, k = idx % 257;
    ps[ii][k] = p[((long)b * T_ + i0 + ii) * 257 + k];
  }
  __syncthreads();
  float acc[16][4] = {};
  int h0 = tid * 4;
  for (int k = 0; k < 257; ++k) {
    float vL[4] = {0.f, 0.f, 0.f, 0.f}, vR[4] = {0.f, 0.f, 0.f, 0.f};
    if (k < 256) {
      short4v v = *reinterpret_cast<const short4v*>(&outL[((long)k * B_ + b) * H_ + h0]);
      vL[0] = us2f((unsigned short)v[0]); vL[1] = us2f((unsigned short)v[1]);
      vL[2] = us2f((unsigned short)v[2]); vL[3] = us2f((unsigned short)v[3]);
    }
    if (k >= 1) {
      short4v v = *reinterpret_cast<const short4v*>(&outR[((long)(k - 1) * B_ + b) * H_ + h0]);
      vR[0] = us2f((unsigned short)v[0]); vR[1] = us2f((unsigned short)v[1]);
      vR[2] = us2f((unsigned short)v[2]); vR[3] = us2f((unsigned short)v[3]);
    }
    #pragma unroll
    for (int ii = 0; ii < 16; ++ii) {
      float pv = ps[ii][k];
      bool useL = (i0 + ii) >= k;
      #pragma unroll
      for (int j = 0; j < 4; ++j)
        acc[ii][j] += pv * (useL ? vL[j] : vR[j]);
    }
  }
  #pragma unroll
  for (int ii = 0; ii < 16; ++ii)
    #pragma unroll
    for (int j = 0; j < 4; ++j)
      h3[((long)(i0 + ii) * B_ + b) * 3 * H_ + 2 * H_ + h0 + j] = f2b(acc[ii][j]);
}

// ---------------------------------------------------------------------------
extern "C" void kernel_launch(void* const* d_in, const int* in_sizes, int n_in,
                              void* d_out, int out_size, void* d_ws, size_t ws_size,
                              hipStream_t stream)
{
  (void)in_sizes; (void)n_in; (void)out_size;
  const int*   data_left  = (const int*)  d_in[0];
  const int*   data_right = (const int*)  d_in[1];
  const float* h0_left    = (const float*)d_in[2];
  const float* c0_left    = (const float*)d_in[3];
  const float* h0_right   = (const float*)d_in[4];
  const float* c0_right   = (const float*)d_in[5];
  const float* emb        = (const float*)d_in[6];
  const float* Wih_l      = (const float*)d_in[7];
  const float* Whh_l      = (const float*)d_in[8];
  const float* bih_l      = (const float*)d_in[9];
  const float* bhh_l      = (const float*)d_in[10];
  const float* Wih_r      = (const float*)d_in[11];
  const float* Whh_r      = (const float*)d_in[12];
  const float* bih_r      = (const float*)d_in[13];
  const float* bhh_r      = (const float*)d_in[14];
  const float* attn_w     = (const float*)d_in[15];
  const float* attn_b     = (const float*)d_in[16];
  const float* trans_w    = (const float*)d_in[17];
  const float* trans_b    = (const float*)d_in[18];
  const float* dec_w      = (const float*)d_in[19];
  const float* dec_b      = (const float*)d_in[20];

  // ---- workspace layout ----
  char* ws = (char*)d_ws;
  bf16*     XL   = (bf16*)    (ws + 0L);
  bf16*     XR   = (bf16*)    (ws + 16777216L);
  bf16*     GI_L = (bf16*)    (ws + 33554432L);
  bf16*     GI_R = (bf16*)    (ws + 100663296L);
  bf16*     H0L  = (bf16*)    (ws + 167772160L);
  bf16*     H0R  = (bf16*)    (ws + 184549376L);
  unsigned* BAR  = (unsigned*)(ws + 201326592L);
  bf16*     WHHB = (bf16*)    (ws + 201588736L);   // 33.6MB, ends 235143168
  bf16*     WIHB   = (bf16*)  (ws + 235143168L);   // 33.6MB, ends 268697600
  bf16*     TRANSB = (bf16*)  (ws + 268697600L);   // 6.3MB,  ends 274989056
  bf16*     DECB   = (bf16*)  (ws + 274989056L);   // 65.5MB, ends 340525056
  const bool fast = ws_size >= 340525056UL;
  // overlays
  bf16*  O1L  = XL;
  bf16*  O1R  = XR;
  bf16*  H3   = GI_L;
  float* P_   = (float*)(ws + 100663296L);
  float* A_   = (float*)(ws + 109084672L);
  float* SL_  = (float*)(ws + 109117440L);
  float* SR_  = (float*)(ws + 109150208L);
  bf16*  PRED = (bf16*) (ws + 109182976L);

  const long BH  = (long)B_ * H_;
  const long WL  = 4L * H_ * H_;
  bf16* WHHB_l = WHHB;
  bf16* WHHB_r = WHHB + 2 * WL;
  bf16* WIHB_l = WIHB;
  bf16* WIHB_r = WIHB + 2 * WL;

  // --- weight conversions ---
  cvt_f32_bf16<<<4096, 256, 0, stream>>>(Whh_l, WHHB_l, 2 * WL);
  cvt_f32_bf16<<<4096, 256, 0, stream>>>(Whh_r, WHHB_r, 2 * WL);
  if (fast) {
    cvt_f32_bf16<<<4096, 256, 0, stream>>>(Wih_l, WIHB_l, 2 * WL);
    cvt_f32_bf16<<<4096, 256, 0, stream>>>(Wih_r, WIHB_r, 2 * WL);
    cvt_f32_bf16<<<1536, 256, 0, stream>>>(trans_w, TRANSB, (long)H_ * 3 * H_);
    cvt_f32_bf16<<<16000, 256, 0, stream>>>(dec_w, DECB, (long)V_ * H_);
  }

  // --- embeddings ---
  embed_gather<<<16384, 128, 0, stream>>>(data_left, data_right, emb, XL, XR);

  // --- layer 0 input GEMMs ---
  if (fast) {
    gemm_bb<0,0,0><<<dim3(64, 32), 256, 0, stream>>>(XL, WIHB_l, nullptr, GI_L, 8192, 4096, 1024);
    gemm_bb<0,0,0><<<dim3(64, 32), 256, 0, stream>>>(XR, WIHB_r, nullptr, GI_R, 8192, 4096, 1024);
  } else {
    gemm_bt<0,0,0><<<dim3(64, 32), 256, 0, stream>>>(XL, Wih_l, nullptr, GI_L, 8192, 4096, 1024);
    gemm_bt<0,0,0><<<dim3(64, 32), 256, 0, stream>>>(XR, Wih_r, nullptr, GI_R, 8192, 4096, 1024);
  }

  // --- layer 0 recurrence (R6 + gi prefetch) ---
  hipMemsetAsync(BAR, 0, 256, stream);
  lstm_layer<<<dim3(64, 2), 256, 0, stream>>>(
      WHHB_l, WHHB_r, GI_L, GI_R,
      bih_l, bhh_l, bih_r, bhh_r,
      h0_left, h0_right, c0_left, c0_right,
      H0L, H0R, 0, BAR);

  // --- layer 1 input GEMMs ---
  if (fast) {
    gemm_bb<0,0,0><<<dim3(64, 32), 256, 0, stream>>>(H0L, WIHB_l + WL, nullptr, GI_L, 8192, 4096, 1024);
    gemm_bb<0,0,0><<<dim3(64, 32), 256, 0, stream>>>(H0R, WIHB_r + WL, nullptr, GI_R, 8192, 4096, 1024);
  } else {
    gemm_bt<0,0,0><<<dim3(64, 32), 256, 0, stream>>>(H0L, Wih_l + WL, nullptr, GI_L, 8192, 4096, 1024);
    gemm_bt<0,0,0><<<dim3(64, 32), 256, 0, stream>>>(H0R, Wih_r + WL, nullptr, GI_R, 8192, 4096, 1024);
  }

  // --- layer 1 recurrence (right dir in original time order) ---
  hipMemsetAsync(BAR, 0, 256, stream);
  lstm_layer<<<dim3(64, 2), 256, 0, stream>>>(
      WHHB_l + WL, WHHB_r + WL, GI_L, GI_R,
      bih_l + 4 * H_, bhh_l + 4 * H_, bih_r + 4 * H_, bhh_r + 4 * H_,
      h0_left + BH, h0_right + BH, c0_left + BH, c0_right + BH,
      O1L, O1R, 1, BAR);

  // --- attention ---
  attn_scores<<<8192, 256, 0, stream>>>(O1L, O1R, attn_w, attn_b, A_, SL_, SR_);
  attn_softmax<<<dim3(256, 32), 64, 0, stream>>>(A_, SL_, SR_, P_);
  h3_copy<<<4096, 256, 0, stream>>>(O1L, O1R, H3);
  attn_cv<<<dim3(16, 32), 256, 0, stream>>>(P_, O1L, O1R, H3);

  // --- trans (tanh) + decode ---
  if (fast) {
    gemm_bb<1,1,0><<<dim3(64, 8),   256, 0, stream>>>(H3,   TRANSB, trans_b, PRED, 8192, 1024, 3072);
    gemm_bb<0,1,1><<<dim3(64, 250), 256, 0, stream>>>(PRED, DECB,   dec_b,   d_out, 8192, 32000, 1024);
  } else {
    gemm_bt<1,1,0><<<dim3(64, 8),   256, 0, stream>>>(H3,   trans_w, trans_b, PRED, 8192, 1024, 3072);
    gemm_bt<0,1,1><<<dim3(64, 250), 256, 0, stream>>>(PRED, dec_w,   dec_b,   d_out, 8192, 32000, 1024);
  }
}